// Round 19
// baseline (161.219 us; speedup 1.0000x reference)
//
#include <hip/hip_runtime.h>
#include <hip/hip_bf16.h>
#include <hip/hip_fp16.h>

// GeneratorSDF: latent-conditioned MLP SDF on a 128^3 grid (fp32 I/O).
// dims: 67 -> 128 -> 64 -> 32 -> 1 (relu, relu, relu, sigmoid)
//
// R19 = R18 (fp16 datapath, 54.9us @ MfmaUtil 31 / VALUBusy 41) + residency 3.
// R18 audit: VALU 54K + MFMA 41K = 71% busy, 29% stall at 2 waves/SIMD; m114
// co-issue floor ~= max(54K,41K) ~= 22us. Need waves. Register demand ~180
// (100 VGPR + 80 AGPR; a2[16]=64) — instead of bounds-forcing (R15/R16 spill),
// REMOVE demand: every wave holds an identical a2 copy, so stream a2 fragments
// from persistent LDS per-use (16 ds_read_b128/ng — R12/R13 proved this DS
// traffic is neutral), keep only a3 in regs. Demand ~116 << 170 budget of
// (256,3): no spill risk. LDS grows to ~48 KB (w2a persistent) -> exactly
// 3 blocks/CU; regs and LDS both land on residency 3 (+50% waves).
// Keeps: fp16 VALU (v_pk_fma_f16/v_pk_max_f16/cvt_pkrtz), grid 1024
// (2048 pts/block, jrow-outer 4x8), pipelined h2 double-buffer + b3f
// prefetch, batched cphase.
// MFMA layouts (verified m89/m91): A[m=lane&15][k=quad*8+j],
// B[k=quad*8+j][n=lane&15], C/D row=quad*4+reg, col=lane&15.

#define NPTS (128 * 128 * 128)

typedef float f32x4_t __attribute__((ext_vector_type(4)));
typedef float f32x2_t __attribute__((ext_vector_type(2)));
typedef __fp16 g16x2_t __attribute__((ext_vector_type(2)));    // VALU half2 (cvt_pkrtz type)
typedef _Float16 h16x8_t __attribute__((ext_vector_type(8)));  // MFMA fragment

__device__ __forceinline__ unsigned h2u(g16x2_t h) {
    unsigned u;
    __builtin_memcpy(&u, &h, 4);
    return u;
}
__device__ __forceinline__ g16x2_t u2h(unsigned u) {
    g16x2_t h;
    __builtin_memcpy(&h, &u, 4);
    return h;
}

__global__ __launch_bounds__(256, 3) void mlp_kernel(
    const float* __restrict__ x,  const float* __restrict__ W1,
    const float* __restrict__ b1, const float* __restrict__ W2,
    const float* __restrict__ b2, const float* __restrict__ W3,
    const float* __restrict__ b3, const float* __restrict__ W4,
    const float* __restrict__ b4, float* __restrict__ out) {
    __shared__ __align__(16) unsigned s_basep[16][64];  // half2 {base[2c],base[2c+1]} per j
    __shared__ __align__(16) unsigned s_wcp[64];        // half2 wc pairs
    __shared__ __align__(16) float s_b2[64];
    __shared__ __align__(16) float s_b3[32];
    __shared__ __align__(16) float s_w4[32];
    // s_u (43 KB): [0..8191] w2a f16 A-frags, PERSISTENT (streamed per-use).
    // [8192..21503] runtime: h2 slots [w][2][16][72] (8192..17407) + zf floats
    // (shorts 17408..21503 = float[4][8][16][4]). w3a staged transiently at
    // [8192..10239], consumed into a3 regs before h2 writes begin.
    __shared__ __align__(16) unsigned short s_u[21504];

    const int t = threadIdx.x;
    const int w = t >> 6;
    const int lane = t & 63;
    const int quad = lane >> 4;
    const int l15 = lane & 15;
    const float step = 2.0f / 127.0f;

    // ================= per-block prep =================
    // Thread t<64 handles channel pair (2t, 2t+1): fold latent + pa + all 16 pb.
    if (t < 64) {
        const float* r0 = W1 + (2 * t) * 67;
        const float* r1 = r0 + 67;
        float s0 = b1[2 * t], s1 = b1[2 * t + 1];
#pragma unroll 8
        for (int c = 0; c < 64; ++c) {
            const float xc = x[c];
            s0 = fmaf(r0[c], xc, s0);
            s1 = fmaf(r1[c], xc, s1);
        }
        const float pa = -1.0f + step * (float)(blockIdx.x >> 3);   // gi
        const float base0 = fmaf(r0[64], pa, s0);
        const float base1 = fmaf(r1[64], pa, s1);
        const float wb0 = r0[65], wb1 = r1[65];
        const int gj0 = (blockIdx.x & 7) * 16;
        s_wcp[t] = h2u(__builtin_amdgcn_cvt_pkrtz(r0[66], r1[66]));
#pragma unroll
        for (int j = 0; j < 16; ++j) {
            const float pb = -1.0f + step * (float)(gj0 + j);
            s_basep[j][t] = h2u(__builtin_amdgcn_cvt_pkrtz(
                fmaf(wb0, pb, base0), fmaf(wb1, pb, base1)));
        }
    }
    // W2 [64][128] -> f16 A-frag staging (persistent at 0..8191)
    const float2* W2v = (const float2*)W2;
#pragma unroll
    for (int it = 0; it < 16; ++it) {
        int pidx = t + 256 * it;
        int idx2 = pidx * 2;
        int o = idx2 >> 7, k = idx2 & 127;
        int mt = o >> 4, lm = o & 15;
        int kb = k >> 5, q = (k >> 3) & 3, jj = k & 7;
        float2 v = W2v[pidx];
        *(unsigned*)&s_u[(mt * 4 + kb) * 512 + (q * 16 + lm) * 8 + jj] =
            h2u(__builtin_amdgcn_cvt_pkrtz(v.x, v.y));
    }
    // W3 [32][64] -> f16 A-frag staging (transient at 8192..10239)
    const float2* W3v = (const float2*)W3;
#pragma unroll
    for (int it = 0; it < 4; ++it) {
        int pidx = t + 256 * it;
        int idx2 = pidx * 2;
        int o = idx2 >> 6, k = idx2 & 63;
        int mt = o >> 4, lm = o & 15;
        int kb = k >> 5, q = (k >> 3) & 3, jj = k & 7;
        float2 v = W3v[pidx];
        *(unsigned*)&s_u[8192 + (mt * 2 + kb) * 512 + (q * 16 + lm) * 8 + jj] =
            h2u(__builtin_amdgcn_cvt_pkrtz(v.x, v.y));
    }
    if (t < 64) s_b2[t] = b2[t];
    if (t < 32) {
        s_b3[t] = b3[t];
        s_w4[t] = W4[t];
    }
    const float bias4 = b4[0];
    __syncthreads();

    // ================= per-wave preload (a3 + biases only; a2 stays in LDS) ====
    h16x8_t a3[4];
#pragma unroll
    for (int f = 0; f < 4; ++f) a3[f] = *(const h16x8_t*)&s_u[8192 + f * 512 + lane * 8];
    f32x4_t b2q[4];
#pragma unroll
    for (int mt = 0; mt < 4; ++mt) b2q[mt] = *(const f32x4_t*)&s_b2[mt * 16 + quad * 4];
    f32x4_t b3q[2];
    f32x2_t w4lo[2], w4hi[2];
#pragma unroll
    for (int mt = 0; mt < 2; ++mt) {
        b3q[mt] = *(const f32x4_t*)&s_b3[mt * 16 + quad * 4];
        float4 wq = *(const float4*)&s_w4[mt * 16 + quad * 4];
        w4lo[mt][0] = wq.x; w4lo[mt][1] = wq.y;
        w4hi[mt][0] = wq.z; w4hi[mt][1] = wq.w;
    }
    // wc pairs: loop-invariant, 16 packed regs, pinned
    unsigned twp[16];
#pragma unroll
    for (int kb = 0; kb < 4; ++kb) {
        uint4 v = *(const uint4*)&s_wcp[kb * 16 + quad * 4];
        twp[kb * 4 + 0] = v.x; twp[kb * 4 + 1] = v.y;
        twp[kb * 4 + 2] = v.z; twp[kb * 4 + 3] = v.w;
    }
#pragma unroll
    for (int i = 0; i < 16; ++i) asm volatile("" : "+v"(twp[i]));
    __syncthreads();  // w3a staging consumed -> region becomes h2/zf scratch

    const int sw = (l15 & 1) * 32;                      // h2 channel swizzle (shorts)
    unsigned short* h2w = &s_u[8192 + w * 2 * 1152];    // 2 slots x 16 pts x 72 shorts
    float* zf = (float*)&s_u[17408];                    // [w][pg&7][i][q]
    const f32x2_t zero2 = {0.0f, 0.0f};
    const g16x2_t zero2h = {(__fp16)0.0f, (__fp16)0.0f};
    const int outbase = blockIdx.x * 2048 + w * 512;

    // B-phase tail: layer 3 + w4-dot using PRELOADED h2 fragments
    auto bphase = [&](int pg, h16x8_t b3f0, h16x8_t b3f1) {
        f32x2_t z2 = zero2;
#pragma unroll
        for (int mt = 0; mt < 2; ++mt) {
            f32x4_t c = b3q[mt];
            c = __builtin_amdgcn_mfma_f32_16x16x32_f16(a3[mt * 2 + 0], b3f0, c, 0, 0, 0);
            c = __builtin_amdgcn_mfma_f32_16x16x32_f16(a3[mt * 2 + 1], b3f1, c, 0, 0, 0);
            f32x2_t h01 = __builtin_elementwise_max((f32x2_t){c[0], c[1]}, zero2);
            f32x2_t h23 = __builtin_elementwise_max((f32x2_t){c[2], c[3]}, zero2);
            z2 = __builtin_elementwise_fma(w4lo[mt], h01, z2);
            z2 = __builtin_elementwise_fma(w4hi[mt], h23, z2);
        }
        zf[w * 512 + (pg & 7) * 64 + l15 * 4 + quad] = z2[0] + z2[1];
    };
    // phase C: batched reduce + sigmoid + coalesced store for an 8-ng batch
    auto cphase = [&](int batch) {
#pragma unroll
        for (int half = 0; half < 2; ++half) {
            const int p = lane + 64 * half;   // point within this batch's 128
            const int pg = p >> 4, i = p & 15;
            float4 v = *(const float4*)&zf[w * 512 + pg * 64 + i * 4];
            float z = (v.x + v.y) + (v.z + v.w) + bias4;
            out[outbase + batch * 128 + p] = 1.0f / (1.0f + __expf(-z));
        }
    };

    // ========== jrow-outer main loop ==========
    for (int jrow = 0; jrow < 4; ++jrow) {
        // base pairs for this jrow: 16 packed regs, pinned
        const unsigned* bp = &s_basep[w * 4 + jrow][0];
        unsigned tbp[16];
#pragma unroll
        for (int kb = 0; kb < 4; ++kb) {
            uint4 v = *(const uint4*)&bp[kb * 16 + quad * 4];
            tbp[kb * 4 + 0] = v.x; tbp[kb * 4 + 1] = v.y;
            tbp[kb * 4 + 2] = v.z; tbp[kb * 4 + 3] = v.w;
        }
#pragma unroll
        for (int i = 0; i < 16; ++i) asm volatile("" : "+v"(tbp[i]));

#pragma unroll 2
        for (int pg = 0; pg < 8; ++pg) {
            const int ng = jrow * 8 + pg;
            // ---- prefetch h2 fragments for bphase(ng-1) ----
            h16x8_t b3f0, b3f1;
            if (ng > 0) {
                const unsigned short* pslot = h2w + ((ng - 1) & 1) * 1152 + l15 * 72;
                b3f0 = *(const h16x8_t*)&pslot[(0 ^ sw) + quad * 8];
                b3f1 = *(const h16x8_t*)&pslot[(32 ^ sw) + quad * 8];
            }

            const float pc = fmaf(step, (float)((pg * 16) + l15), -1.0f);
            const g16x2_t pc2 = __builtin_amdgcn_cvt_pkrtz(pc, pc);

            // ---- A: h1 via packed f16 fma/max, straight into B-fragments ----
            h16x8_t bfrag[4];
#pragma unroll
            for (int kb = 0; kb < 4; ++kb) {
                union { h16x8_t v; g16x2_t h[4]; } bb;
#pragma unroll
                for (int p = 0; p < 4; ++p) {
                    g16x2_t hh = __builtin_elementwise_fma(
                        u2h(twp[kb * 4 + p]), pc2, u2h(tbp[kb * 4 + p]));
                    bb.h[p] = __builtin_elementwise_max(hh, zero2h);
                }
                bfrag[kb] = bb.v;
            }
            // ---- A: layer 2 MFMA (f16), A-fragments STREAMED from LDS ----
            f32x4_t acc2[4];
#pragma unroll
            for (int mt = 0; mt < 4; ++mt) {
                f32x4_t c = b2q[mt];
#pragma unroll
                for (int kb = 0; kb < 4; ++kb) {
                    h16x8_t a2f = *(const h16x8_t*)&s_u[(mt * 4 + kb) * 512 + lane * 8];
                    c = __builtin_amdgcn_mfma_f32_16x16x32_f16(a2f, bfrag[kb], c, 0, 0, 0);
                }
                acc2[mt] = c;
            }
            // ---- A: pack (cvt_pkrtz) + relu (pk_max_f16) + write h2 slot ----
            unsigned short* slot = h2w + (ng & 1) * 1152 + l15 * 72;
#pragma unroll
            for (int mt = 0; mt < 4; ++mt) {
                g16x2_t lo = __builtin_elementwise_max(
                    __builtin_amdgcn_cvt_pkrtz(acc2[mt][0], acc2[mt][1]), zero2h);
                g16x2_t hi = __builtin_elementwise_max(
                    __builtin_amdgcn_cvt_pkrtz(acc2[mt][2], acc2[mt][3]), zero2h);
                uint2 pk;
                pk.x = h2u(lo);
                pk.y = h2u(hi);
                *(uint2*)&slot[(mt * 16 + quad * 4) ^ sw] = pk;
            }
            // ---- B for previous group (fragments already in registers) ----
            if (ng > 0) {
                bphase(ng - 1, b3f0, b3f1);
                if (((ng - 1) & 7) == 7) cphase((ng - 1) >> 3);
            }
        }
    }
    {   // drain: bphase(31) with direct reads
        const unsigned short* pslot = h2w + (31 & 1) * 1152 + l15 * 72;
        h16x8_t b3f0 = *(const h16x8_t*)&pslot[(0 ^ sw) + quad * 8];
        h16x8_t b3f1 = *(const h16x8_t*)&pslot[(32 ^ sw) + quad * 8];
        bphase(31, b3f0, b3f1);
        cphase(3);
    }
}

extern "C" void kernel_launch(void* const* d_in, const int* in_sizes, int n_in,
                              void* d_out, int out_size, void* d_ws, size_t ws_size,
                              hipStream_t stream) {
    mlp_kernel<<<NPTS / 2048, 256, 0, stream>>>(
        (const float*)d_in[0], (const float*)d_in[1], (const float*)d_in[2],
        (const float*)d_in[3], (const float*)d_in[4], (const float*)d_in[5],
        (const float*)d_in[6], (const float*)d_in[7], (const float*)d_in[8],
        (float*)d_out);
}

// Round 20
// 131.460 us; speedup vs baseline: 1.2264x; 1.2264x over previous
//
#include <hip/hip_runtime.h>
#include <hip/hip_bf16.h>
#include <hip/hip_fp16.h>

// GeneratorSDF: latent-conditioned MLP SDF on a 128^3 grid (fp32 I/O).
// dims: 67 -> 128 -> 64 -> 32 -> 1 (relu, relu, relu, sigmoid)
//
// R20: residency-3, attempt 4 — with the allocator DECODED. All (256,3)
// attempts gave VGPR=84 = 168/2: with any AGPR use the compiler splits the
// budget evenly (84 arch + 84 accum) and spills arch demand above 84 (spill
// sizes ordered by overage: R15 474MB > R16 34MB > R19 10.7MB). So: drive
// VGPR demand <= 84. R20 = R19 (a2 streamed from persistent LDS) MINUS all
// remaining register tables: tbp/twp pins -> per-use packed uint4 LDS reads
// (R13: table reads neutral); b2q/b3q/w4 -> per-use quad-uniform LDS reads
// (2-way banked = free). Demand ~65-80 VGPR + 16 AGPR. LDS 48KB -> 3
// blocks/CU; regs + LDS both land on 3 waves/SIMD (+50% vs R18's 2).
// Keeps: fp16 datapath (R18's 54.9us win), pipelined h2 double-buffer + b3f
// prefetch, batched cphase, grid 1024 (2048 pts/block).
// MFMA layouts (verified m89/m91): A[m=lane&15][k=quad*8+j],
// B[k=quad*8+j][n=lane&15], C/D row=quad*4+reg, col=lane&15.

#define NPTS (128 * 128 * 128)

typedef float f32x4_t __attribute__((ext_vector_type(4)));
typedef float f32x2_t __attribute__((ext_vector_type(2)));
typedef __fp16 g16x2_t __attribute__((ext_vector_type(2)));    // VALU half2 (cvt_pkrtz type)
typedef _Float16 h16x8_t __attribute__((ext_vector_type(8)));  // MFMA fragment

__device__ __forceinline__ unsigned h2u(g16x2_t h) {
    unsigned u;
    __builtin_memcpy(&u, &h, 4);
    return u;
}
__device__ __forceinline__ g16x2_t u2h(unsigned u) {
    g16x2_t h;
    __builtin_memcpy(&h, &u, 4);
    return h;
}

__global__ __launch_bounds__(256, 3) void mlp_kernel(
    const float* __restrict__ x,  const float* __restrict__ W1,
    const float* __restrict__ b1, const float* __restrict__ W2,
    const float* __restrict__ b2, const float* __restrict__ W3,
    const float* __restrict__ b3, const float* __restrict__ W4,
    const float* __restrict__ b4, float* __restrict__ out) {
    __shared__ __align__(16) unsigned s_basep[16][64];  // half2 {base[2c],base[2c+1]} per j
    __shared__ __align__(16) unsigned s_wcp[64];        // half2 wc pairs
    __shared__ __align__(16) float s_b2[64];
    __shared__ __align__(16) float s_b3[32];
    __shared__ __align__(16) float s_w4[32];
    // s_u (43 KB): [0..8191] w2a f16 A-frags, PERSISTENT (streamed per-use).
    // [8192..21503] runtime: h2 slots [w][2][16][72] (8192..17407) + zf floats
    // (shorts 17408..21503 = float[4][8][16][4]). w3a staged transiently at
    // [8192..10239], consumed into a3 regs before h2 writes begin.
    __shared__ __align__(16) unsigned short s_u[21504];

    const int t = threadIdx.x;
    const int w = t >> 6;
    const int lane = t & 63;
    const int quad = lane >> 4;
    const int l15 = lane & 15;
    const float step = 2.0f / 127.0f;

    // ================= per-block prep =================
    // Thread t<64 handles channel pair (2t, 2t+1): fold latent + pa + all 16 pb.
    if (t < 64) {
        const float* r0 = W1 + (2 * t) * 67;
        const float* r1 = r0 + 67;
        float s0 = b1[2 * t], s1 = b1[2 * t + 1];
#pragma unroll 8
        for (int c = 0; c < 64; ++c) {
            const float xc = x[c];
            s0 = fmaf(r0[c], xc, s0);
            s1 = fmaf(r1[c], xc, s1);
        }
        const float pa = -1.0f + step * (float)(blockIdx.x >> 3);   // gi
        const float base0 = fmaf(r0[64], pa, s0);
        const float base1 = fmaf(r1[64], pa, s1);
        const float wb0 = r0[65], wb1 = r1[65];
        const int gj0 = (blockIdx.x & 7) * 16;
        s_wcp[t] = h2u(__builtin_amdgcn_cvt_pkrtz(r0[66], r1[66]));
#pragma unroll
        for (int j = 0; j < 16; ++j) {
            const float pb = -1.0f + step * (float)(gj0 + j);
            s_basep[j][t] = h2u(__builtin_amdgcn_cvt_pkrtz(
                fmaf(wb0, pb, base0), fmaf(wb1, pb, base1)));
        }
    }
    // W2 [64][128] -> f16 A-frag staging (persistent at 0..8191)
    const float2* W2v = (const float2*)W2;
#pragma unroll
    for (int it = 0; it < 16; ++it) {
        int pidx = t + 256 * it;
        int idx2 = pidx * 2;
        int o = idx2 >> 7, k = idx2 & 127;
        int mt = o >> 4, lm = o & 15;
        int kb = k >> 5, q = (k >> 3) & 3, jj = k & 7;
        float2 v = W2v[pidx];
        *(unsigned*)&s_u[(mt * 4 + kb) * 512 + (q * 16 + lm) * 8 + jj] =
            h2u(__builtin_amdgcn_cvt_pkrtz(v.x, v.y));
    }
    // W3 [32][64] -> f16 A-frag staging (transient at 8192..10239)
    const float2* W3v = (const float2*)W3;
#pragma unroll
    for (int it = 0; it < 4; ++it) {
        int pidx = t + 256 * it;
        int idx2 = pidx * 2;
        int o = idx2 >> 6, k = idx2 & 63;
        int mt = o >> 4, lm = o & 15;
        int kb = k >> 5, q = (k >> 3) & 3, jj = k & 7;
        float2 v = W3v[pidx];
        *(unsigned*)&s_u[8192 + (mt * 2 + kb) * 512 + (q * 16 + lm) * 8 + jj] =
            h2u(__builtin_amdgcn_cvt_pkrtz(v.x, v.y));
    }
    if (t < 64) s_b2[t] = b2[t];
    if (t < 32) {
        s_b3[t] = b3[t];
        s_w4[t] = W4[t];
    }
    const float bias4 = b4[0];
    __syncthreads();

    // ================= per-wave preload: a3 ONLY (16 AGPR) =================
    h16x8_t a3[4];
#pragma unroll
    for (int f = 0; f < 4; ++f) a3[f] = *(const h16x8_t*)&s_u[8192 + f * 512 + lane * 8];
    __syncthreads();  // w3a staging consumed -> region becomes h2/zf scratch

    const int sw = (l15 & 1) * 32;                      // h2 channel swizzle (shorts)
    unsigned short* h2w = &s_u[8192 + w * 2 * 1152];    // 2 slots x 16 pts x 72 shorts
    float* zf = (float*)&s_u[17408];                    // [w][pg&7][i][q]
    const f32x2_t zero2 = {0.0f, 0.0f};
    const g16x2_t zero2h = {(__fp16)0.0f, (__fp16)0.0f};
    const int outbase = blockIdx.x * 2048 + w * 512;

    // B-phase tail: layer 3 + w4-dot; biases/w4 read per-use (quad-uniform, free)
    auto bphase = [&](int pg, h16x8_t b3f0, h16x8_t b3f1) {
        f32x2_t z2 = zero2;
#pragma unroll
        for (int mt = 0; mt < 2; ++mt) {
            f32x4_t c = *(const f32x4_t*)&s_b3[mt * 16 + quad * 4];
            c = __builtin_amdgcn_mfma_f32_16x16x32_f16(a3[mt * 2 + 0], b3f0, c, 0, 0, 0);
            c = __builtin_amdgcn_mfma_f32_16x16x32_f16(a3[mt * 2 + 1], b3f1, c, 0, 0, 0);
            float4 wq = *(const float4*)&s_w4[mt * 16 + quad * 4];
            f32x2_t h01 = __builtin_elementwise_max((f32x2_t){c[0], c[1]}, zero2);
            f32x2_t h23 = __builtin_elementwise_max((f32x2_t){c[2], c[3]}, zero2);
            z2 = __builtin_elementwise_fma((f32x2_t){wq.x, wq.y}, h01, z2);
            z2 = __builtin_elementwise_fma((f32x2_t){wq.z, wq.w}, h23, z2);
        }
        zf[w * 512 + (pg & 7) * 64 + l15 * 4 + quad] = z2[0] + z2[1];
    };
    // phase C: batched reduce + sigmoid + coalesced store for an 8-ng batch
    auto cphase = [&](int batch) {
#pragma unroll
        for (int half = 0; half < 2; ++half) {
            const int p = lane + 64 * half;   // point within this batch's 128
            const int pg = p >> 4, i = p & 15;
            float4 v = *(const float4*)&zf[w * 512 + pg * 64 + i * 4];
            float z = (v.x + v.y) + (v.z + v.w) + bias4;
            out[outbase + batch * 128 + p] = 1.0f / (1.0f + __expf(-z));
        }
    };

    // ========== pipelined main loop: prefetch b3f(ng-1), A(ng), B(ng-1) ==========
#pragma unroll 2
    for (int ng = 0; ng < 32; ++ng) {
        // ---- prefetch h2 fragments for bphase(ng-1) ----
        h16x8_t b3f0, b3f1;
        if (ng > 0) {
            const unsigned short* pslot = h2w + ((ng - 1) & 1) * 1152 + l15 * 72;
            b3f0 = *(const h16x8_t*)&pslot[(0 ^ sw) + quad * 8];
            b3f1 = *(const h16x8_t*)&pslot[(32 ^ sw) + quad * 8];
        }

        const unsigned* bp = &s_basep[w * 4 + (ng >> 3)][0];
        const float pc = fmaf(step, (float)(((ng & 7) * 16) + l15), -1.0f);
        const g16x2_t pc2 = __builtin_amdgcn_cvt_pkrtz(pc, pc);

        // ---- A: h1 via packed f16 fma/max; tables read per-use from LDS ----
        h16x8_t bfrag[4];
#pragma unroll
        for (int kb = 0; kb < 4; ++kb) {
            uint4 tv = *(const uint4*)&s_wcp[kb * 16 + quad * 4];
            uint4 bv = *(const uint4*)&bp[kb * 16 + quad * 4];
            union { h16x8_t v; g16x2_t h[4]; } bb;
            bb.h[0] = __builtin_elementwise_max(
                __builtin_elementwise_fma(u2h(tv.x), pc2, u2h(bv.x)), zero2h);
            bb.h[1] = __builtin_elementwise_max(
                __builtin_elementwise_fma(u2h(tv.y), pc2, u2h(bv.y)), zero2h);
            bb.h[2] = __builtin_elementwise_max(
                __builtin_elementwise_fma(u2h(tv.z), pc2, u2h(bv.z)), zero2h);
            bb.h[3] = __builtin_elementwise_max(
                __builtin_elementwise_fma(u2h(tv.w), pc2, u2h(bv.w)), zero2h);
            bfrag[kb] = bb.v;
        }
        // ---- A: layer 2 MFMA; A-frags streamed from LDS, bias C-init per-use ----
        f32x4_t acc2[4];
#pragma unroll
        for (int mt = 0; mt < 4; ++mt) {
            f32x4_t c = *(const f32x4_t*)&s_b2[mt * 16 + quad * 4];
#pragma unroll
            for (int kb = 0; kb < 4; ++kb) {
                h16x8_t a2f = *(const h16x8_t*)&s_u[(mt * 4 + kb) * 512 + lane * 8];
                c = __builtin_amdgcn_mfma_f32_16x16x32_f16(a2f, bfrag[kb], c, 0, 0, 0);
            }
            acc2[mt] = c;
        }
        // ---- A: pack (cvt_pkrtz) + relu (pk_max_f16) + write h2 slot ----
        unsigned short* slot = h2w + (ng & 1) * 1152 + l15 * 72;
#pragma unroll
        for (int mt = 0; mt < 4; ++mt) {
            g16x2_t lo = __builtin_elementwise_max(
                __builtin_amdgcn_cvt_pkrtz(acc2[mt][0], acc2[mt][1]), zero2h);
            g16x2_t hi = __builtin_elementwise_max(
                __builtin_amdgcn_cvt_pkrtz(acc2[mt][2], acc2[mt][3]), zero2h);
            uint2 pk;
            pk.x = h2u(lo);
            pk.y = h2u(hi);
            *(uint2*)&slot[(mt * 16 + quad * 4) ^ sw] = pk;
        }
        // ---- B for previous group (fragments already in registers) ----
        if (ng > 0) {
            bphase(ng - 1, b3f0, b3f1);
            if (((ng - 1) & 7) == 7) cphase((ng - 1) >> 3);
        }
    }
    {   // drain: bphase(31) with direct reads
        const unsigned short* pslot = h2w + (31 & 1) * 1152 + l15 * 72;
        h16x8_t b3f0 = *(const h16x8_t*)&pslot[(0 ^ sw) + quad * 8];
        h16x8_t b3f1 = *(const h16x8_t*)&pslot[(32 ^ sw) + quad * 8];
        bphase(31, b3f0, b3f1);
        cphase(3);
    }
}

extern "C" void kernel_launch(void* const* d_in, const int* in_sizes, int n_in,
                              void* d_out, int out_size, void* d_ws, size_t ws_size,
                              hipStream_t stream) {
    mlp_kernel<<<NPTS / 2048, 256, 0, stream>>>(
        (const float*)d_in[0], (const float*)d_in[1], (const float*)d_in[2],
        (const float*)d_in[3], (const float*)d_in[4], (const float*)d_in[5],
        (const float*)d_in[6], (const float*)d_in[7], (const float*)d_in[8],
        (float*)d_out);
}

// Round 21
// 116.049 us; speedup vs baseline: 1.3892x; 1.1328x over previous
//
#include <hip/hip_runtime.h>
#include <hip/hip_bf16.h>
#include <hip/hip_fp16.h>

// GeneratorSDF: latent-conditioned MLP SDF on a 128^3 grid (fp32 I/O).
// dims: 67 -> 128 -> 64 -> 32 -> 1 (relu, relu, relu, sigmoid)
//
// R21 = R18 (best: 54.9us @ MfmaUtil 31 / VALUBusy 41, 2 waves/SIMD) with ONE
// change: bphase(ng-1) hoisted BETWEEN the L2 MFMAs and the pack. R20 closed
// the residency question: streaming a2 from LDS to reach 3 waves/SIMD costs
// more (ds latency inside the MFMA chain, 72.5us) than the wave buys; and
// (256,3) with register a2 always spills (allocator splits 168 evenly at
// 84 VGPR + 84 AGPR; demand ~180). So optimize AT 2 waves: bphase depends
// only on preloaded b3f/a3/b3q registers — independent of acc2 — so running
// it before the pack fills the acc2 MFMA-latency shadow with real work.
// Slot disjointness unchanged (bphase reads (ng-1)&1, pack writes ng&1).
// Keeps from R18: fp16 datapath (v_pk_fma_f16/v_pk_max_f16/cvt_pkrtz),
// a2[16]+a3[4] register-resident, pinned twp/tbp tables, jrow-outer 4x8,
// pipelined h2 double-buffer + b3f prefetch, batched cphase, LDS union,
// (256,2), grid 1024 (2048 pts/block).
// MFMA layouts (verified m89/m91): A[m=lane&15][k=quad*8+j],
// B[k=quad*8+j][n=lane&15], C/D row=quad*4+reg, col=lane&15.

#define NPTS (128 * 128 * 128)

typedef float f32x4_t __attribute__((ext_vector_type(4)));
typedef float f32x2_t __attribute__((ext_vector_type(2)));
typedef __fp16 g16x2_t __attribute__((ext_vector_type(2)));    // VALU half2 (cvt_pkrtz type)
typedef _Float16 h16x8_t __attribute__((ext_vector_type(8)));  // MFMA fragment

__device__ __forceinline__ unsigned h2u(g16x2_t h) {
    unsigned u;
    __builtin_memcpy(&u, &h, 4);
    return u;
}
__device__ __forceinline__ g16x2_t u2h(unsigned u) {
    g16x2_t h;
    __builtin_memcpy(&h, &u, 4);
    return h;
}

__global__ __launch_bounds__(256, 2) void mlp_kernel(
    const float* __restrict__ x,  const float* __restrict__ W1,
    const float* __restrict__ b1, const float* __restrict__ W2,
    const float* __restrict__ b2, const float* __restrict__ W3,
    const float* __restrict__ b3, const float* __restrict__ W4,
    const float* __restrict__ b4, float* __restrict__ out) {
    __shared__ __align__(16) unsigned s_basep[16][64];  // half2 {base[2c],base[2c+1]} per j
    __shared__ __align__(16) unsigned s_wcp[64];        // half2 wc pairs
    __shared__ __align__(16) float s_b2[64];
    __shared__ __align__(16) float s_b3[32];
    __shared__ __align__(16) float s_w4[32];
    // Union (26.6 KB): staging = w2a[16][64][8] halves (0..8191) + w3a[4][64][8]
    // (8192..10239); runtime = h2 slots [w][2][16][72] (0..9215) + zf floats
    // (shorts 9216..13311 = float[4][8][16][4] : w*512 + pg*64 + i*4 + q).
    __shared__ __align__(16) unsigned short s_u[13312];

    const int t = threadIdx.x;
    const int w = t >> 6;
    const int lane = t & 63;
    const int quad = lane >> 4;
    const int l15 = lane & 15;
    const float step = 2.0f / 127.0f;

    // ================= per-block prep =================
    // Thread t<64 handles channel pair (2t, 2t+1): fold latent + pa + all 16 pb.
    if (t < 64) {
        const float* r0 = W1 + (2 * t) * 67;
        const float* r1 = r0 + 67;
        float s0 = b1[2 * t], s1 = b1[2 * t + 1];
#pragma unroll 8
        for (int c = 0; c < 64; ++c) {
            const float xc = x[c];
            s0 = fmaf(r0[c], xc, s0);
            s1 = fmaf(r1[c], xc, s1);
        }
        const float pa = -1.0f + step * (float)(blockIdx.x >> 3);   // gi
        const float base0 = fmaf(r0[64], pa, s0);
        const float base1 = fmaf(r1[64], pa, s1);
        const float wb0 = r0[65], wb1 = r1[65];
        const int gj0 = (blockIdx.x & 7) * 16;
        s_wcp[t] = h2u(__builtin_amdgcn_cvt_pkrtz(r0[66], r1[66]));
#pragma unroll
        for (int j = 0; j < 16; ++j) {
            const float pb = -1.0f + step * (float)(gj0 + j);
            s_basep[j][t] = h2u(__builtin_amdgcn_cvt_pkrtz(
                fmaf(wb0, pb, base0), fmaf(wb1, pb, base1)));
        }
    }
    // W2 [64][128] -> f16 A-frag staging (pairs along k)
    const float2* W2v = (const float2*)W2;
#pragma unroll
    for (int it = 0; it < 16; ++it) {
        int pidx = t + 256 * it;
        int idx2 = pidx * 2;
        int o = idx2 >> 7, k = idx2 & 127;
        int mt = o >> 4, lm = o & 15;
        int kb = k >> 5, q = (k >> 3) & 3, jj = k & 7;
        float2 v = W2v[pidx];
        *(unsigned*)&s_u[(mt * 4 + kb) * 512 + (q * 16 + lm) * 8 + jj] =
            h2u(__builtin_amdgcn_cvt_pkrtz(v.x, v.y));
    }
    // W3 [32][64] -> f16 A-frag staging
    const float2* W3v = (const float2*)W3;
#pragma unroll
    for (int it = 0; it < 4; ++it) {
        int pidx = t + 256 * it;
        int idx2 = pidx * 2;
        int o = idx2 >> 6, k = idx2 & 63;
        int mt = o >> 4, lm = o & 15;
        int kb = k >> 5, q = (k >> 3) & 3, jj = k & 7;
        float2 v = W3v[pidx];
        *(unsigned*)&s_u[8192 + (mt * 2 + kb) * 512 + (q * 16 + lm) * 8 + jj] =
            h2u(__builtin_amdgcn_cvt_pkrtz(v.x, v.y));
    }
    if (t < 64) s_b2[t] = b2[t];
    if (t < 32) {
        s_b3[t] = b3[t];
        s_w4[t] = W4[t];
    }
    const float bias4 = b4[0];
    __syncthreads();

    // ================= per-wave fragment preload =================
    h16x8_t a2[16];
#pragma unroll
    for (int f = 0; f < 16; ++f) a2[f] = *(const h16x8_t*)&s_u[f * 512 + lane * 8];
    h16x8_t a3[4];
#pragma unroll
    for (int f = 0; f < 4; ++f) a3[f] = *(const h16x8_t*)&s_u[8192 + f * 512 + lane * 8];
    f32x4_t b2q[4];
#pragma unroll
    for (int mt = 0; mt < 4; ++mt) b2q[mt] = *(const f32x4_t*)&s_b2[mt * 16 + quad * 4];
    f32x4_t b3q[2];
    f32x2_t w4lo[2], w4hi[2];
#pragma unroll
    for (int mt = 0; mt < 2; ++mt) {
        b3q[mt] = *(const f32x4_t*)&s_b3[mt * 16 + quad * 4];
        float4 wq = *(const float4*)&s_w4[mt * 16 + quad * 4];
        w4lo[mt][0] = wq.x; w4lo[mt][1] = wq.y;
        w4hi[mt][0] = wq.z; w4hi[mt][1] = wq.w;
    }
    // wc pairs: loop-invariant, 16 packed regs, pinned
    unsigned twp[16];
#pragma unroll
    for (int kb = 0; kb < 4; ++kb) {
        uint4 v = *(const uint4*)&s_wcp[kb * 16 + quad * 4];
        twp[kb * 4 + 0] = v.x; twp[kb * 4 + 1] = v.y;
        twp[kb * 4 + 2] = v.z; twp[kb * 4 + 3] = v.w;
    }
#pragma unroll
    for (int i = 0; i < 16; ++i) asm volatile("" : "+v"(twp[i]));
    __syncthreads();  // union handoff: staging -> h2/zf scratch

    const int sw = (l15 & 1) * 32;                    // h2 channel swizzle (shorts)
    unsigned short* h2w = &s_u[w * 2 * 1152];         // 2 slots x 16 pts x 72 shorts
    float* zf = (float*)&s_u[9216];                   // [w][pg&7][i][q]
    const f32x2_t zero2 = {0.0f, 0.0f};
    const g16x2_t zero2h = {(__fp16)0.0f, (__fp16)0.0f};
    const int outbase = blockIdx.x * 2048 + w * 512;

    // B-phase tail: layer 3 + w4-dot using PRELOADED h2 fragments
    auto bphase = [&](int pg, h16x8_t b3f0, h16x8_t b3f1) {
        f32x2_t z2 = zero2;
#pragma unroll
        for (int mt = 0; mt < 2; ++mt) {
            f32x4_t c = b3q[mt];
            c = __builtin_amdgcn_mfma_f32_16x16x32_f16(a3[mt * 2 + 0], b3f0, c, 0, 0, 0);
            c = __builtin_amdgcn_mfma_f32_16x16x32_f16(a3[mt * 2 + 1], b3f1, c, 0, 0, 0);
            f32x2_t h01 = __builtin_elementwise_max((f32x2_t){c[0], c[1]}, zero2);
            f32x2_t h23 = __builtin_elementwise_max((f32x2_t){c[2], c[3]}, zero2);
            z2 = __builtin_elementwise_fma(w4lo[mt], h01, z2);
            z2 = __builtin_elementwise_fma(w4hi[mt], h23, z2);
        }
        zf[w * 512 + (pg & 7) * 64 + l15 * 4 + quad] = z2[0] + z2[1];
    };
    // phase C: batched reduce + sigmoid + coalesced store for an 8-ng batch
    auto cphase = [&](int batch) {
#pragma unroll
        for (int half = 0; half < 2; ++half) {
            const int p = lane + 64 * half;   // point within this batch's 128
            const int pg = p >> 4, i = p & 15;
            float4 v = *(const float4*)&zf[w * 512 + pg * 64 + i * 4];
            float z = (v.x + v.y) + (v.z + v.w) + bias4;
            out[outbase + batch * 128 + p] = 1.0f / (1.0f + __expf(-z));
        }
    };

    // ========== jrow-outer main loop ==========
    for (int jrow = 0; jrow < 4; ++jrow) {
        // base pairs for this jrow: 16 packed regs, pinned
        const unsigned* bp = &s_basep[w * 4 + jrow][0];
        unsigned tbp[16];
#pragma unroll
        for (int kb = 0; kb < 4; ++kb) {
            uint4 v = *(const uint4*)&bp[kb * 16 + quad * 4];
            tbp[kb * 4 + 0] = v.x; tbp[kb * 4 + 1] = v.y;
            tbp[kb * 4 + 2] = v.z; tbp[kb * 4 + 3] = v.w;
        }
#pragma unroll
        for (int i = 0; i < 16; ++i) asm volatile("" : "+v"(tbp[i]));

#pragma unroll 2
        for (int pg = 0; pg < 8; ++pg) {
            const int ng = jrow * 8 + pg;
            // ---- prefetch h2 fragments for bphase(ng-1) ----
            h16x8_t b3f0, b3f1;
            if (ng > 0) {
                const unsigned short* pslot = h2w + ((ng - 1) & 1) * 1152 + l15 * 72;
                b3f0 = *(const h16x8_t*)&pslot[(0 ^ sw) + quad * 8];
                b3f1 = *(const h16x8_t*)&pslot[(32 ^ sw) + quad * 8];
            }

            const float pc = fmaf(step, (float)((pg * 16) + l15), -1.0f);
            const g16x2_t pc2 = __builtin_amdgcn_cvt_pkrtz(pc, pc);

            // ---- A1: h1 via packed f16 fma/max, straight into B-fragments ----
            h16x8_t bfrag[4];
#pragma unroll
            for (int kb = 0; kb < 4; ++kb) {
                union { h16x8_t v; g16x2_t h[4]; } bb;
#pragma unroll
                for (int p = 0; p < 4; ++p) {
                    g16x2_t hh = __builtin_elementwise_fma(
                        u2h(twp[kb * 4 + p]), pc2, u2h(tbp[kb * 4 + p]));
                    bb.h[p] = __builtin_elementwise_max(hh, zero2h);
                }
                bfrag[kb] = bb.v;
            }
            // ---- A2: layer 2 MFMA (f16), bias in C-init ----
            f32x4_t acc2[4];
#pragma unroll
            for (int mt = 0; mt < 4; ++mt) {
                f32x4_t c = b2q[mt];
#pragma unroll
                for (int kb = 0; kb < 4; ++kb)
                    c = __builtin_amdgcn_mfma_f32_16x16x32_f16(a2[mt * 4 + kb], bfrag[kb], c, 0, 0, 0);
                acc2[mt] = c;
            }
            // ---- B(ng-1) HOISTED into the acc2 latency shadow: depends only on
            // b3f/a3/b3q registers, not acc2; reads slot (ng-1)&1, pack writes
            // slot ng&1 — disjoint ----
            if (ng > 0) bphase(ng - 1, b3f0, b3f1);
            // ---- A3: pack (cvt_pkrtz) + relu (pk_max_f16) + write h2 slot ----
            unsigned short* slot = h2w + (ng & 1) * 1152 + l15 * 72;
#pragma unroll
            for (int mt = 0; mt < 4; ++mt) {
                g16x2_t lo = __builtin_elementwise_max(
                    __builtin_amdgcn_cvt_pkrtz(acc2[mt][0], acc2[mt][1]), zero2h);
                g16x2_t hi = __builtin_elementwise_max(
                    __builtin_amdgcn_cvt_pkrtz(acc2[mt][2], acc2[mt][3]), zero2h);
                uint2 pk;
                pk.x = h2u(lo);
                pk.y = h2u(hi);
                *(uint2*)&slot[(mt * 16 + quad * 4) ^ sw] = pk;
            }
            // ---- batch flush (reads zf written by bphase(ng-1)) ----
            if (ng > 0 && ((ng - 1) & 7) == 7) cphase((ng - 1) >> 3);
        }
    }
    {   // drain: bphase(31) with direct reads
        const unsigned short* pslot = h2w + (31 & 1) * 1152 + l15 * 72;
        h16x8_t b3f0 = *(const h16x8_t*)&pslot[(0 ^ sw) + quad * 8];
        h16x8_t b3f1 = *(const h16x8_t*)&pslot[(32 ^ sw) + quad * 8];
        bphase(31, b3f0, b3f1);
        cphase(3);
    }
}

extern "C" void kernel_launch(void* const* d_in, const int* in_sizes, int n_in,
                              void* d_out, int out_size, void* d_ws, size_t ws_size,
                              hipStream_t stream) {
    mlp_kernel<<<NPTS / 2048, 256, 0, stream>>>(
        (const float*)d_in[0], (const float*)d_in[1], (const float*)d_in[2],
        (const float*)d_in[3], (const float*)d_in[4], (const float*)d_in[5],
        (const float*)d_in[6], (const float*)d_in[7], (const float*)d_in[8],
        (float*)d_out);
}

// Round 22
// 112.274 us; speedup vs baseline: 1.4359x; 1.0336x over previous
//
#include <hip/hip_runtime.h>
#include <hip/hip_bf16.h>
#include <hip/hip_fp16.h>

// GeneratorSDF: latent-conditioned MLP SDF on a 128^3 grid (fp32 I/O).
// dims: 67 -> 128 -> 64 -> 32 -> 1 (relu, relu, relu, sigmoid)
//
// R22 = R18 (best: 54.9us @ MfmaUtil 31 / VALUBusy 41) + 4-way-parallel prep
// fold. R21 (bphase hoist) was slightly negative -> original order restored;
// the compiler's scheduler owns intra-body ordering (5 neutral scheduling
// experiments: R9/R12/R13/R14/R21). Residency is hard-capped at 2 waves/SIMD
// (a2=64 AGPR irreducible; (256,3) splits 168->84+84 and spills (R15/R16);
// LDS-streaming a2 regresses (R20)). Remaining lever: the W1-fold was a
// 64-iteration serial chain on t<64 while 192 threads idled (~3-5% of
// runtime). Now: all 256 threads compute 16-term partials (channel-pair
// p=t&63, c-range h=t>>6) into LDS; t<64 combines. Chain 4x shorter.
// Keeps from R18: fp16 datapath (v_pk_fma_f16/v_pk_max_f16/cvt_pkrtz),
// a2[16]+a3[4] register-resident, pinned twp/tbp tables, jrow-outer 4x8,
// pipelined h2 double-buffer + b3f prefetch, batched cphase, LDS union,
// (256,2), grid 1024 (2048 pts/block).
// MFMA layouts (verified m89/m91): A[m=lane&15][k=quad*8+j],
// B[k=quad*8+j][n=lane&15], C/D row=quad*4+reg, col=lane&15.

#define NPTS (128 * 128 * 128)

typedef float f32x4_t __attribute__((ext_vector_type(4)));
typedef float f32x2_t __attribute__((ext_vector_type(2)));
typedef __fp16 g16x2_t __attribute__((ext_vector_type(2)));    // VALU half2 (cvt_pkrtz type)
typedef _Float16 h16x8_t __attribute__((ext_vector_type(8)));  // MFMA fragment

__device__ __forceinline__ unsigned h2u(g16x2_t h) {
    unsigned u;
    __builtin_memcpy(&u, &h, 4);
    return u;
}
__device__ __forceinline__ g16x2_t u2h(unsigned u) {
    g16x2_t h;
    __builtin_memcpy(&h, &u, 4);
    return h;
}

__global__ __launch_bounds__(256, 2) void mlp_kernel(
    const float* __restrict__ x,  const float* __restrict__ W1,
    const float* __restrict__ b1, const float* __restrict__ W2,
    const float* __restrict__ b2, const float* __restrict__ W3,
    const float* __restrict__ b3, const float* __restrict__ W4,
    const float* __restrict__ b4, float* __restrict__ out) {
    __shared__ __align__(16) unsigned s_basep[16][64];  // half2 {base[2c],base[2c+1]} per j
    __shared__ __align__(16) unsigned s_wcp[64];        // half2 wc pairs
    __shared__ __align__(16) float s_b2[64];
    __shared__ __align__(16) float s_b3[32];
    __shared__ __align__(16) float s_w4[32];
    // Union (26.6 KB): staging = w2a[16][64][8] halves (0..8191) + w3a[4][64][8]
    // (8192..10239) + W1-fold partials (floats at shorts 10240..11263, transient);
    // runtime = h2 slots [w][2][16][72] (0..9215) + zf floats
    // (shorts 9216..13311 = float[4][8][16][4] : w*512 + pg*64 + i*4 + q).
    __shared__ __align__(16) unsigned short s_u[13312];

    const int t = threadIdx.x;
    const int w = t >> 6;
    const int lane = t & 63;
    const int quad = lane >> 4;
    const int l15 = lane & 15;
    const float step = 2.0f / 127.0f;

    // ================= per-block prep, phase 1 (all 256 threads) =============
    // W1 fold partials: thread covers channel-pair p = t&63, c in [h*16,(h+1)*16)
    {
        const int p = t & 63, h = t >> 6;
        const float* r0 = W1 + (2 * p) * 67 + h * 16;
        const float* r1 = r0 + 67;
        const float* xh = x + h * 16;
        float s0 = 0.0f, s1 = 0.0f;
#pragma unroll
        for (int c = 0; c < 16; ++c) {
            const float xc = xh[c];
            s0 = fmaf(r0[c], xc, s0);
            s1 = fmaf(r1[c], xc, s1);
        }
        float2* psum = (float2*)&s_u[10240];   // [h][p], 4 x 64 float2
        psum[h * 64 + p] = make_float2(s0, s1);
    }
    // W2 [64][128] -> f16 A-frag staging (pairs along k)
    const float2* W2v = (const float2*)W2;
#pragma unroll
    for (int it = 0; it < 16; ++it) {
        int pidx = t + 256 * it;
        int idx2 = pidx * 2;
        int o = idx2 >> 7, k = idx2 & 127;
        int mt = o >> 4, lm = o & 15;
        int kb = k >> 5, q = (k >> 3) & 3, jj = k & 7;
        float2 v = W2v[pidx];
        *(unsigned*)&s_u[(mt * 4 + kb) * 512 + (q * 16 + lm) * 8 + jj] =
            h2u(__builtin_amdgcn_cvt_pkrtz(v.x, v.y));
    }
    // W3 [32][64] -> f16 A-frag staging
    const float2* W3v = (const float2*)W3;
#pragma unroll
    for (int it = 0; it < 4; ++it) {
        int pidx = t + 256 * it;
        int idx2 = pidx * 2;
        int o = idx2 >> 6, k = idx2 & 63;
        int mt = o >> 4, lm = o & 15;
        int kb = k >> 5, q = (k >> 3) & 3, jj = k & 7;
        float2 v = W3v[pidx];
        *(unsigned*)&s_u[8192 + (mt * 2 + kb) * 512 + (q * 16 + lm) * 8 + jj] =
            h2u(__builtin_amdgcn_cvt_pkrtz(v.x, v.y));
    }
    if (t < 64) s_b2[t] = b2[t];
    if (t < 32) {
        s_b3[t] = b3[t];
        s_w4[t] = W4[t];
    }
    const float bias4 = b4[0];
    __syncthreads();

    // ================= prep phase 2 (t<64): combine partials + pack tables ====
    if (t < 64) {
        const float2* psum = (const float2*)&s_u[10240];
        float2 q0 = psum[t], q1 = psum[64 + t], q2 = psum[128 + t], q3 = psum[192 + t];
        float s0 = b1[2 * t] + (q0.x + q1.x) + (q2.x + q3.x);
        float s1 = b1[2 * t + 1] + (q0.y + q1.y) + (q2.y + q3.y);
        const float* r0 = W1 + (2 * t) * 67;
        const float* r1 = r0 + 67;
        const float pa = -1.0f + step * (float)(blockIdx.x >> 3);   // gi
        const float base0 = fmaf(r0[64], pa, s0);
        const float base1 = fmaf(r1[64], pa, s1);
        const float wb0 = r0[65], wb1 = r1[65];
        const int gj0 = (blockIdx.x & 7) * 16;
        s_wcp[t] = h2u(__builtin_amdgcn_cvt_pkrtz(r0[66], r1[66]));
#pragma unroll
        for (int j = 0; j < 16; ++j) {
            const float pb = -1.0f + step * (float)(gj0 + j);
            s_basep[j][t] = h2u(__builtin_amdgcn_cvt_pkrtz(
                fmaf(wb0, pb, base0), fmaf(wb1, pb, base1)));
        }
    }
    __syncthreads();

    // ================= per-wave fragment preload =================
    h16x8_t a2[16];
#pragma unroll
    for (int f = 0; f < 16; ++f) a2[f] = *(const h16x8_t*)&s_u[f * 512 + lane * 8];
    h16x8_t a3[4];
#pragma unroll
    for (int f = 0; f < 4; ++f) a3[f] = *(const h16x8_t*)&s_u[8192 + f * 512 + lane * 8];
    f32x4_t b2q[4];
#pragma unroll
    for (int mt = 0; mt < 4; ++mt) b2q[mt] = *(const f32x4_t*)&s_b2[mt * 16 + quad * 4];
    f32x4_t b3q[2];
    f32x2_t w4lo[2], w4hi[2];
#pragma unroll
    for (int mt = 0; mt < 2; ++mt) {
        b3q[mt] = *(const f32x4_t*)&s_b3[mt * 16 + quad * 4];
        float4 wq = *(const float4*)&s_w4[mt * 16 + quad * 4];
        w4lo[mt][0] = wq.x; w4lo[mt][1] = wq.y;
        w4hi[mt][0] = wq.z; w4hi[mt][1] = wq.w;
    }
    // wc pairs: loop-invariant, 16 packed regs, pinned
    unsigned twp[16];
#pragma unroll
    for (int kb = 0; kb < 4; ++kb) {
        uint4 v = *(const uint4*)&s_wcp[kb * 16 + quad * 4];
        twp[kb * 4 + 0] = v.x; twp[kb * 4 + 1] = v.y;
        twp[kb * 4 + 2] = v.z; twp[kb * 4 + 3] = v.w;
    }
#pragma unroll
    for (int i = 0; i < 16; ++i) asm volatile("" : "+v"(twp[i]));
    __syncthreads();  // union handoff: staging -> h2/zf scratch

    const int sw = (l15 & 1) * 32;                    // h2 channel swizzle (shorts)
    unsigned short* h2w = &s_u[w * 2 * 1152];         // 2 slots x 16 pts x 72 shorts
    float* zf = (float*)&s_u[9216];                   // [w][pg&7][i][q]
    const f32x2_t zero2 = {0.0f, 0.0f};
    const g16x2_t zero2h = {(__fp16)0.0f, (__fp16)0.0f};
    const int outbase = blockIdx.x * 2048 + w * 512;

    // B-phase tail: layer 3 + w4-dot using PRELOADED h2 fragments
    auto bphase = [&](int pg, h16x8_t b3f0, h16x8_t b3f1) {
        f32x2_t z2 = zero2;
#pragma unroll
        for (int mt = 0; mt < 2; ++mt) {
            f32x4_t c = b3q[mt];
            c = __builtin_amdgcn_mfma_f32_16x16x32_f16(a3[mt * 2 + 0], b3f0, c, 0, 0, 0);
            c = __builtin_amdgcn_mfma_f32_16x16x32_f16(a3[mt * 2 + 1], b3f1, c, 0, 0, 0);
            f32x2_t h01 = __builtin_elementwise_max((f32x2_t){c[0], c[1]}, zero2);
            f32x2_t h23 = __builtin_elementwise_max((f32x2_t){c[2], c[3]}, zero2);
            z2 = __builtin_elementwise_fma(w4lo[mt], h01, z2);
            z2 = __builtin_elementwise_fma(w4hi[mt], h23, z2);
        }
        zf[w * 512 + (pg & 7) * 64 + l15 * 4 + quad] = z2[0] + z2[1];
    };
    // phase C: batched reduce + sigmoid + coalesced store for an 8-ng batch
    auto cphase = [&](int batch) {
#pragma unroll
        for (int half = 0; half < 2; ++half) {
            const int p = lane + 64 * half;   // point within this batch's 128
            const int pg = p >> 4, i = p & 15;
            float4 v = *(const float4*)&zf[w * 512 + pg * 64 + i * 4];
            float z = (v.x + v.y) + (v.z + v.w) + bias4;
            out[outbase + batch * 128 + p] = 1.0f / (1.0f + __expf(-z));
        }
    };

    // ========== jrow-outer main loop ==========
    for (int jrow = 0; jrow < 4; ++jrow) {
        // base pairs for this jrow: 16 packed regs, pinned
        const unsigned* bp = &s_basep[w * 4 + jrow][0];
        unsigned tbp[16];
#pragma unroll
        for (int kb = 0; kb < 4; ++kb) {
            uint4 v = *(const uint4*)&bp[kb * 16 + quad * 4];
            tbp[kb * 4 + 0] = v.x; tbp[kb * 4 + 1] = v.y;
            tbp[kb * 4 + 2] = v.z; tbp[kb * 4 + 3] = v.w;
        }
#pragma unroll
        for (int i = 0; i < 16; ++i) asm volatile("" : "+v"(tbp[i]));

#pragma unroll 2
        for (int pg = 0; pg < 8; ++pg) {
            const int ng = jrow * 8 + pg;
            // ---- prefetch h2 fragments for bphase(ng-1) ----
            h16x8_t b3f0, b3f1;
            if (ng > 0) {
                const unsigned short* pslot = h2w + ((ng - 1) & 1) * 1152 + l15 * 72;
                b3f0 = *(const h16x8_t*)&pslot[(0 ^ sw) + quad * 8];
                b3f1 = *(const h16x8_t*)&pslot[(32 ^ sw) + quad * 8];
            }

            const float pc = fmaf(step, (float)((pg * 16) + l15), -1.0f);
            const g16x2_t pc2 = __builtin_amdgcn_cvt_pkrtz(pc, pc);

            // ---- A1: h1 via packed f16 fma/max, straight into B-fragments ----
            h16x8_t bfrag[4];
#pragma unroll
            for (int kb = 0; kb < 4; ++kb) {
                union { h16x8_t v; g16x2_t h[4]; } bb;
#pragma unroll
                for (int p = 0; p < 4; ++p) {
                    g16x2_t hh = __builtin_elementwise_fma(
                        u2h(twp[kb * 4 + p]), pc2, u2h(tbp[kb * 4 + p]));
                    bb.h[p] = __builtin_elementwise_max(hh, zero2h);
                }
                bfrag[kb] = bb.v;
            }
            // ---- A2: layer 2 MFMA (f16), bias in C-init ----
            f32x4_t acc2[4];
#pragma unroll
            for (int mt = 0; mt < 4; ++mt) {
                f32x4_t c = b2q[mt];
#pragma unroll
                for (int kb = 0; kb < 4; ++kb)
                    c = __builtin_amdgcn_mfma_f32_16x16x32_f16(a2[mt * 4 + kb], bfrag[kb], c, 0, 0, 0);
                acc2[mt] = c;
            }
            // ---- A3: pack (cvt_pkrtz) + relu (pk_max_f16) + write h2 slot ----
            unsigned short* slot = h2w + (ng & 1) * 1152 + l15 * 72;
#pragma unroll
            for (int mt = 0; mt < 4; ++mt) {
                g16x2_t lo = __builtin_elementwise_max(
                    __builtin_amdgcn_cvt_pkrtz(acc2[mt][0], acc2[mt][1]), zero2h);
                g16x2_t hi = __builtin_elementwise_max(
                    __builtin_amdgcn_cvt_pkrtz(acc2[mt][2], acc2[mt][3]), zero2h);
                uint2 pk;
                pk.x = h2u(lo);
                pk.y = h2u(hi);
                *(uint2*)&slot[(mt * 16 + quad * 4) ^ sw] = pk;
            }
            // ---- B for previous group (fragments already in registers) ----
            if (ng > 0) {
                bphase(ng - 1, b3f0, b3f1);
                if (((ng - 1) & 7) == 7) cphase((ng - 1) >> 3);
            }
        }
    }
    {   // drain: bphase(31) with direct reads
        const unsigned short* pslot = h2w + (31 & 1) * 1152 + l15 * 72;
        h16x8_t b3f0 = *(const h16x8_t*)&pslot[(0 ^ sw) + quad * 8];
        h16x8_t b3f1 = *(const h16x8_t*)&pslot[(32 ^ sw) + quad * 8];
        bphase(31, b3f0, b3f1);
        cphase(3);
    }
}

extern "C" void kernel_launch(void* const* d_in, const int* in_sizes, int n_in,
                              void* d_out, int out_size, void* d_ws, size_t ws_size,
                              hipStream_t stream) {
    mlp_kernel<<<NPTS / 2048, 256, 0, stream>>>(
        (const float*)d_in[0], (const float*)d_in[1], (const float*)d_in[2],
        (const float*)d_in[3], (const float*)d_in[4], (const float*)d_in[5],
        (const float*)d_in[6], (const float*)d_in[7], (const float*)d_in[8],
        (float*)d_out);
}